// Round 9
// baseline (71.537 us; speedup 1.0000x reference)
//
#include <hip/hip_runtime.h>
#include <hip/hip_bf16.h>

#define NN 8192
#define EE 524288
#define D_IN 3
#define D_HID 16
#define D_OUT 16
#define NAGG (NN * D_IN)        // 24576 floats
#define SLICES 64               // edge slices
#define QSPLIT 4                // node-range quarters
#define EPS_SLICE (EE / SLICES) // 8192 edges per slice
#define NODES_Q (NN / QSPLIT)   // 2048 nodes per quarter
#define LELE (NODES_Q * D_IN)   // 6144 floats = 24 KB LDS
#define ROWS_PER_BLK 8          // outer: rows per block
#define OUTER_THREADS 512

typedef float f32x4 __attribute__((ext_vector_type(4)));

// ---------------- shared device MLP ----------------
__device__ __forceinline__ float mlp_eval(float z0, float z1, float z2,
        const float* __restrict__ W1, const float* __restrict__ b1,
        const float* __restrict__ W2, const float* __restrict__ b2,
        const float* __restrict__ W3, const float* __restrict__ b3) {
    float h1[D_HID];
#pragma unroll
    for (int j = 0; j < D_HID; ++j) {
        float v = b1[j] + z0 * W1[0 * D_HID + j] + z1 * W1[1 * D_HID + j] + z2 * W1[2 * D_HID + j];
        h1[j] = v > 0.0f ? v : 0.0f;
    }
    float h2[D_OUT];
#pragma unroll
    for (int j = 0; j < D_OUT; ++j) {
        float v = b2[j];
#pragma unroll
        for (int k = 0; k < D_HID; ++k) v += h1[k] * W2[k * D_OUT + j];
        h2[j] = v > 0.0f ? v : 0.0f;
    }
    float v = b3[0];
#pragma unroll
    for (int k = 0; k < D_OUT; ++k) v += h2[k] * W3[k];
    return v > 0.0f ? v : 0.0f;
}

// ---------------- kernel 1: LDS-privatized scatter, 256 blocks ----------------
__global__ __launch_bounds__(512) void scatter_priv_kernel(
        const float* __restrict__ nf,
        const int* __restrict__ eidx,
        float* __restrict__ partials) {
    __shared__ float lagg[LELE];
    const int tid = threadIdx.x;
    const int slice = blockIdx.x & (SLICES - 1);
    const int q = blockIdx.x >> 6;
    for (int i = tid; i < LELE; i += 512) lagg[i] = 0.0f;
    __syncthreads();

    const int base = slice * EPS_SLICE;
    const int nlo = q * NODES_Q;
    for (int e = base + tid; e < base + EPS_SLICE; e += 512) {
        int d = eidx[EE + e];          // dst row
        unsigned dq = (unsigned)(d - nlo);
        if (dq < (unsigned)NODES_Q) {
            int s = eidx[e];           // src row
            atomicAdd(&lagg[dq * 3 + 0], nf[s * 3 + 0]);
            atomicAdd(&lagg[dq * 3 + 1], nf[s * 3 + 1]);
            atomicAdd(&lagg[dq * 3 + 2], nf[s * 3 + 2]);
        }
    }
    __syncthreads();

    f32x4* __restrict__ dst = (f32x4*)(partials + (size_t)slice * NAGG + (size_t)nlo * D_IN);
    const f32x4* __restrict__ src = (const f32x4*)lagg;
    for (int i = tid; i < LELE / 4; i += 512) dst[i] = src[i];
}

// ---------------- kernel 2: fused reduce + MLP ----------------
// 32 blocks x 256 threads. Block b owns nodes [b*256, b*256+256) = float4
// columns [b*192, b*192+192). Phase 1: 192 threads sum 64 partial rows
// (coalesced) into LDS. Phase 2: 256 threads run the MLP from LDS.
__global__ __launch_bounds__(256) void reduce_mlp_fused_kernel(
        const float* __restrict__ partials,
        const float* __restrict__ nf,
        const float* __restrict__ epsp,
        const float* __restrict__ W1, const float* __restrict__ b1,
        const float* __restrict__ W2, const float* __restrict__ b2,
        const float* __restrict__ W3, const float* __restrict__ b3,
        float* __restrict__ h) {
    __shared__ f32x4 lz[192];
    const int t = threadIdx.x;
    if (t < 192) {
        const f32x4* __restrict__ p = (const f32x4*)partials;
        const int c4 = blockIdx.x * 192 + t;
        f32x4 s = {0.0f, 0.0f, 0.0f, 0.0f};
#pragma unroll 8
        for (int k = 0; k < SLICES; ++k)
            s += p[(size_t)k * (NAGG / 4) + c4];
        lz[t] = s;
    }
    __syncthreads();

    const int node = blockIdx.x * 256 + t;
    const float* __restrict__ l = (const float*)lz;
    const float eps1 = 1.0f + epsp[0];
    float z0 = eps1 * nf[node * 3 + 0] + l[t * 3 + 0];
    float z1 = eps1 * nf[node * 3 + 1] + l[t * 3 + 1];
    float z2 = eps1 * nf[node * 3 + 2] + l[t * 3 + 2];
    h[node] = mlp_eval(z0, z1, z2, W1, b1, W2, b2, W3, b3);
}

// ---------------- fallback path (ws too small): zero + global atomics -------
__global__ void zero_agg_kernel(float* __restrict__ agg, int n) {
    int i = blockIdx.x * blockDim.x + threadIdx.x;
    if (i < n) agg[i] = 0.0f;
}

__global__ void scatter_atomic_kernel(const float* __restrict__ nf,
                                      const int* __restrict__ eidx,
                                      float* __restrict__ agg) {
    int e = blockIdx.x * blockDim.x + threadIdx.x;
    if (e >= EE) return;
    int s = eidx[e];
    int d = eidx[EE + e];
    atomicAdd(&agg[d * 3 + 0], nf[s * 3 + 0]);
    atomicAdd(&agg[d * 3 + 1], nf[s * 3 + 1]);
    atomicAdd(&agg[d * 3 + 2], nf[s * 3 + 2]);
}

__global__ void mlp_kernel(const float* __restrict__ nf,
                           const float* __restrict__ agg,
                           const float* __restrict__ epsp,
                           const float* __restrict__ W1, const float* __restrict__ b1,
                           const float* __restrict__ W2, const float* __restrict__ b2,
                           const float* __restrict__ W3, const float* __restrict__ b3,
                           float* __restrict__ h) {
    int i = blockIdx.x * blockDim.x + threadIdx.x;
    if (i >= NN) return;
    float eps1 = 1.0f + epsp[0];
    float z0 = eps1 * nf[i * 3 + 0] + agg[i * 3 + 0];
    float z1 = eps1 * nf[i * 3 + 1] + agg[i * 3 + 1];
    float z2 = eps1 * nf[i * 3 + 2] + agg[i * 3 + 2];
    h[i] = mlp_eval(z0, z1, z2, W1, b1, W2, b2, W3, b3);
}

// ---------------- kernel 3: outer product, 8 rows/block, contiguous ----------
__global__ __launch_bounds__(OUTER_THREADS) void outer_kernel(
        const float* __restrict__ h, f32x4* __restrict__ out) {
    const int r0 = blockIdx.x * ROWS_PER_BLK;
    float hi[ROWS_PER_BLK];
#pragma unroll
    for (int r = 0; r < ROWS_PER_BLK; ++r) hi[r] = h[r0 + r];
    const f32x4* __restrict__ h4 = (const f32x4*)h;
    f32x4* __restrict__ base = out + (size_t)r0 * (NN / 4);
#pragma unroll 4
    for (int j = threadIdx.x; j < NN / 4; j += OUTER_THREADS) {
        f32x4 v = h4[j];
#pragma unroll
        for (int r = 0; r < ROWS_PER_BLK; ++r)
            base[(size_t)r * (NN / 4) + j] = v * hi[r];
    }
}

extern "C" void kernel_launch(void* const* d_in, const int* in_sizes, int n_in,
                              void* d_out, int out_size, void* d_ws, size_t ws_size,
                              hipStream_t stream) {
    const float* nf   = (const float*)d_in[0];
    const int*   eidx = (const int*)d_in[1];
    const float* eps  = (const float*)d_in[2];
    const float* W1   = (const float*)d_in[3];
    const float* b1   = (const float*)d_in[4];
    const float* W2   = (const float*)d_in[5];
    const float* b2   = (const float*)d_in[6];
    const float* W3   = (const float*)d_in[7];
    const float* b3   = (const float*)d_in[8];
    float* out = (float*)d_out;

    float* h        = (float*)d_ws;                      // NN floats
    float* agg      = h + NN;                            // NAGG floats (fallback)
    float* partials = agg + NAGG;                        // SLICES*NAGG floats

    size_t need = (size_t)(NN + NAGG + (size_t)SLICES * NAGG) * sizeof(float);

    if (ws_size >= need) {
        scatter_priv_kernel<<<SLICES * QSPLIT, 512, 0, stream>>>(nf, eidx, partials);
        reduce_mlp_fused_kernel<<<NN / 256, 256, 0, stream>>>(
            partials, nf, eps, W1, b1, W2, b2, W3, b3, h);
    } else {
        zero_agg_kernel<<<(NAGG + 255) / 256, 256, 0, stream>>>(agg, NAGG);
        scatter_atomic_kernel<<<(EE + 255) / 256, 256, 0, stream>>>(nf, eidx, agg);
        mlp_kernel<<<(NN + 255) / 256, 256, 0, stream>>>(nf, agg, eps, W1, b1, W2, b2, W3, b3, h);
    }
    outer_kernel<<<NN / ROWS_PER_BLK, OUTER_THREADS, 0, stream>>>(h, (f32x4*)out);
}

// Round 10
// 66.272 us; speedup vs baseline: 1.0794x; 1.0794x over previous
//
#include <hip/hip_runtime.h>
#include <hip/hip_bf16.h>

#define NN 8192
#define EE 524288
#define D_IN 3
#define D_HID 16
#define D_OUT 16
#define NAGG (NN * D_IN)        // 24576 floats
#define NAGG4 (NAGG / 4)        // 6144 f32x4
#define SLICES 64               // edge slices
#define QSPLIT 4                // node-range quarters
#define EPS_SLICE (EE / SLICES) // 8192 edges per slice
#define NODES_Q (NN / QSPLIT)   // 2048 nodes per quarter
#define LELE (NODES_Q * D_IN)   // 6144 floats = 24 KB LDS
#define ROWS_PER_BLK 4          // outer: rows per block (R7-proven)
#define NPB 64                  // fused reduce+mlp: nodes per block
#define C4B (NPB * D_IN / 4)    // 48 f32x4 columns per block
#define RCHUNK 4                // row chunks in fused reduce

typedef float f32x4 __attribute__((ext_vector_type(4)));

// ---------------- shared device MLP ----------------
__device__ __forceinline__ float mlp_eval(float z0, float z1, float z2,
        const float* __restrict__ W1, const float* __restrict__ b1,
        const float* __restrict__ W2, const float* __restrict__ b2,
        const float* __restrict__ W3, const float* __restrict__ b3) {
    float h1[D_HID];
#pragma unroll
    for (int j = 0; j < D_HID; ++j) {
        float v = b1[j] + z0 * W1[0 * D_HID + j] + z1 * W1[1 * D_HID + j] + z2 * W1[2 * D_HID + j];
        h1[j] = v > 0.0f ? v : 0.0f;
    }
    float h2[D_OUT];
#pragma unroll
    for (int j = 0; j < D_OUT; ++j) {
        float v = b2[j];
#pragma unroll
        for (int k = 0; k < D_HID; ++k) v += h1[k] * W2[k * D_OUT + j];
        h2[j] = v > 0.0f ? v : 0.0f;
    }
    float v = b3[0];
#pragma unroll
    for (int k = 0; k < D_OUT; ++k) v += h2[k] * W3[k];
    return v > 0.0f ? v : 0.0f;
}

// ---------------- kernel 1: LDS-privatized scatter, 256 blocks (R7) ----------
__global__ __launch_bounds__(512) void scatter_priv_kernel(
        const float* __restrict__ nf,
        const int* __restrict__ eidx,
        float* __restrict__ partials) {
    __shared__ float lagg[LELE];
    const int tid = threadIdx.x;
    const int slice = blockIdx.x & (SLICES - 1);
    const int q = blockIdx.x >> 6;
    for (int i = tid; i < LELE; i += 512) lagg[i] = 0.0f;
    __syncthreads();

    const int base = slice * EPS_SLICE;
    const int nlo = q * NODES_Q;
    for (int e = base + tid; e < base + EPS_SLICE; e += 512) {
        int d = eidx[EE + e];          // dst row
        unsigned dq = (unsigned)(d - nlo);
        if (dq < (unsigned)NODES_Q) {
            int s = eidx[e];           // src row
            atomicAdd(&lagg[dq * 3 + 0], nf[s * 3 + 0]);
            atomicAdd(&lagg[dq * 3 + 1], nf[s * 3 + 1]);
            atomicAdd(&lagg[dq * 3 + 2], nf[s * 3 + 2]);
        }
    }
    __syncthreads();

    f32x4* __restrict__ dst = (f32x4*)(partials + (size_t)slice * NAGG + (size_t)nlo * D_IN);
    const f32x4* __restrict__ src = (const f32x4*)lagg;
    for (int i = tid; i < LELE / 4; i += 512) dst[i] = src[i];
}

// ---------------- kernel 2: fused reduce + MLP, 128 blocks ----------------
// Block b owns nodes [b*64, b*64+64) = f32x4 columns [b*48, b*48+48).
// Phase 1: 192 threads = 48 cols x 4 chunks; each sums 16 rows, coalesced.
// LDS tree combine; phase 2: 64 threads run the MLP.
__global__ __launch_bounds__(256) void reduce_mlp_fused_kernel(
        const float* __restrict__ partials,
        const float* __restrict__ nf,
        const float* __restrict__ epsp,
        const float* __restrict__ W1, const float* __restrict__ b1,
        const float* __restrict__ W2, const float* __restrict__ b2,
        const float* __restrict__ W3, const float* __restrict__ b3,
        float* __restrict__ h) {
    __shared__ f32x4 lq[C4B * RCHUNK];   // 192 f32x4
    __shared__ f32x4 lz[C4B];            // 48 f32x4
    const int t = threadIdx.x;
    if (t < C4B * RCHUNK) {
        const int q  = t / C4B;          // row chunk 0..3
        const int cl = t % C4B;          // col 0..47 (consecutive lanes -> coalesced)
        const int c4 = blockIdx.x * C4B + cl;
        const f32x4* __restrict__ p = (const f32x4*)partials;
        f32x4 s = {0.0f, 0.0f, 0.0f, 0.0f};
#pragma unroll
        for (int k = 0; k < SLICES / RCHUNK; ++k)
            s += p[(size_t)(q * (SLICES / RCHUNK) + k) * NAGG4 + c4];
        lq[cl * RCHUNK + q] = s;
    }
    __syncthreads();
    if (t < C4B) {
        lz[t] = lq[t * RCHUNK + 0] + lq[t * RCHUNK + 1] +
                lq[t * RCHUNK + 2] + lq[t * RCHUNK + 3];
    }
    __syncthreads();

    if (t < NPB) {
        const int node = blockIdx.x * NPB + t;
        const float* __restrict__ l = (const float*)lz;
        const float eps1 = 1.0f + epsp[0];
        float z0 = eps1 * nf[node * 3 + 0] + l[t * 3 + 0];
        float z1 = eps1 * nf[node * 3 + 1] + l[t * 3 + 1];
        float z2 = eps1 * nf[node * 3 + 2] + l[t * 3 + 2];
        h[node] = mlp_eval(z0, z1, z2, W1, b1, W2, b2, W3, b3);
    }
}

// ---------------- fallback path (ws too small): zero + global atomics -------
__global__ void zero_agg_kernel(float* __restrict__ agg, int n) {
    int i = blockIdx.x * blockDim.x + threadIdx.x;
    if (i < n) agg[i] = 0.0f;
}

__global__ void scatter_atomic_kernel(const float* __restrict__ nf,
                                      const int* __restrict__ eidx,
                                      float* __restrict__ agg) {
    int e = blockIdx.x * blockDim.x + threadIdx.x;
    if (e >= EE) return;
    int s = eidx[e];
    int d = eidx[EE + e];
    atomicAdd(&agg[d * 3 + 0], nf[s * 3 + 0]);
    atomicAdd(&agg[d * 3 + 1], nf[s * 3 + 1]);
    atomicAdd(&agg[d * 3 + 2], nf[s * 3 + 2]);
}

__global__ void mlp_kernel(const float* __restrict__ nf,
                           const float* __restrict__ agg,
                           const float* __restrict__ epsp,
                           const float* __restrict__ W1, const float* __restrict__ b1,
                           const float* __restrict__ W2, const float* __restrict__ b2,
                           const float* __restrict__ W3, const float* __restrict__ b3,
                           float* __restrict__ h) {
    int i = blockIdx.x * blockDim.x + threadIdx.x;
    if (i >= NN) return;
    float eps1 = 1.0f + epsp[0];
    float z0 = eps1 * nf[i * 3 + 0] + agg[i * 3 + 0];
    float z1 = eps1 * nf[i * 3 + 1] + agg[i * 3 + 1];
    float z2 = eps1 * nf[i * 3 + 2] + agg[i * 3 + 2];
    h[i] = mlp_eval(z0, z1, z2, W1, b1, W2, b2, W3, b3);
}

// ---------------- kernel 3: outer product, 4 rows/block, contiguous (R7) ----
__global__ __launch_bounds__(256) void outer_kernel(const float* __restrict__ h,
                                                    f32x4* __restrict__ out) {
    const int r0 = blockIdx.x * ROWS_PER_BLK;
    const float hi0 = h[r0 + 0];
    const float hi1 = h[r0 + 1];
    const float hi2 = h[r0 + 2];
    const float hi3 = h[r0 + 3];
    const f32x4* __restrict__ h4 = (const f32x4*)h;
    f32x4* __restrict__ row0 = out + (size_t)r0 * (NN / 4);
    f32x4* __restrict__ row1 = row0 + (NN / 4);
    f32x4* __restrict__ row2 = row1 + (NN / 4);
    f32x4* __restrict__ row3 = row2 + (NN / 4);
#pragma unroll 8
    for (int j = threadIdx.x; j < NN / 4; j += 256) {
        f32x4 v = h4[j];
        row0[j] = v * hi0;
        row1[j] = v * hi1;
        row2[j] = v * hi2;
        row3[j] = v * hi3;
    }
}

extern "C" void kernel_launch(void* const* d_in, const int* in_sizes, int n_in,
                              void* d_out, int out_size, void* d_ws, size_t ws_size,
                              hipStream_t stream) {
    const float* nf   = (const float*)d_in[0];
    const int*   eidx = (const int*)d_in[1];
    const float* eps  = (const float*)d_in[2];
    const float* W1   = (const float*)d_in[3];
    const float* b1   = (const float*)d_in[4];
    const float* W2   = (const float*)d_in[5];
    const float* b2   = (const float*)d_in[6];
    const float* W3   = (const float*)d_in[7];
    const float* b3   = (const float*)d_in[8];
    float* out = (float*)d_out;

    float* h        = (float*)d_ws;                      // NN floats
    float* agg      = h + NN;                            // NAGG floats (fallback)
    float* partials = agg + NAGG;                        // SLICES*NAGG floats

    size_t need = (size_t)(NN + NAGG + (size_t)SLICES * NAGG) * sizeof(float);

    if (ws_size >= need) {
        scatter_priv_kernel<<<SLICES * QSPLIT, 512, 0, stream>>>(nf, eidx, partials);
        reduce_mlp_fused_kernel<<<NN / NPB, 256, 0, stream>>>(
            partials, nf, eps, W1, b1, W2, b2, W3, b3, h);
    } else {
        zero_agg_kernel<<<(NAGG + 255) / 256, 256, 0, stream>>>(agg, NAGG);
        scatter_atomic_kernel<<<(EE + 255) / 256, 256, 0, stream>>>(nf, eidx, agg);
        mlp_kernel<<<(NN + 255) / 256, 256, 0, stream>>>(nf, agg, eps, W1, b1, W2, b2, W3, b3, h);
    }
    outer_kernel<<<NN / ROWS_PER_BLK, 256, 0, stream>>>(h, (f32x4*)out);
}